// Round 1
// baseline (280.595 us; speedup 1.0000x reference)
//
#include <hip/hip_runtime.h>

#define N_SAMP 48
#define TPR 4               // threads per ray
#define SPT (N_SAMP / TPR)  // samples per thread = 12
#define RPB 64              // rays per block
#define BLOCK (RPB * TPR)   // 256 threads

// No LDS: each thread loads its own 12-sample fragment directly from global
// with float4 loads. A wave's 64 lanes cover a dense 3 KB (z/sigma) or 9 KB
// (rgb) region across the k-unrolled loads, so L1 merges the stride-3/stride-9
// float4 pattern into full cache-line utilization. Dropping the 60 KB LDS
// staging lifts occupancy from 2 blocks/CU (8 waves) to the VGPR limit
// (~20 waves/CU), which is what a latency-bound kernel needs.
__global__ __launch_bounds__(BLOCK) void volrender_kernel(
    const float4* __restrict__ rgb4,    // n_rays * 36 float4
    const float4* __restrict__ sigma4,  // n_rays * 12 float4
    const float4* __restrict__ z4,      // n_rays * 12 float4
    float* __restrict__ out_rgb,        // n_rays * 3 floats
    float* __restrict__ out_depth,      // n_rays floats
    int n_rays)
{
    const int t   = threadIdx.x;
    const int rl  = t >> 2;      // ray within block
    const int q   = t & 3;       // quarter of the ray
    const int ray = blockIdx.x * RPB + rl;

    // Clamp (not early-return) so wave-wide shuffles stay uniform even if a
    // partial block ever exists; stores are guarded below.
    const int rayc = (ray < n_rays) ? ray : (n_rays - 1);

    // ---- global -> registers: this thread's 12-sample fragment ----
    float rloc[SPT * 3];
    float4* rv = reinterpret_cast<float4*>(rloc);
    {
        const size_t rb = (size_t)rayc * 36 + (size_t)q * 9;
#pragma unroll
        for (int k = 0; k < 9; ++k) rv[k] = rgb4[rb + k];
    }

    float zloc[SPT];
    float4* zv = reinterpret_cast<float4*>(zloc);
    float sloc[SPT];
    float4* sv = reinterpret_cast<float4*>(sloc);
    {
        const size_t zb = (size_t)rayc * 12 + (size_t)q * 3;
#pragma unroll
        for (int k = 0; k < 3; ++k) zv[k] = z4[zb + k];
#pragma unroll
        for (int k = 0; k < 3; ++k) sv[k] = sigma4[zb + k];
    }

    // first z of the NEXT quarter: neighbor lane's zloc[0]
    const int lane    = threadIdx.x & 63;
    const float znext = __shfl(zloc[0], (lane + 1) & 63);  // unused for q==3

    // ---- local pass: exclusive-T weights within the 12-sample segment ----
    float T = 1.0f;
    float ar = 0.0f, ag = 0.0f, ab = 0.0f, ad = 0.0f;
#pragma unroll
    for (int j = 0; j < SPT; ++j) {
        const float zn   = (j < SPT - 1) ? zloc[j + 1] : znext;
        const bool  last = (j == SPT - 1);
        float dist  = (last && q == TPR - 1) ? 1e10f : (zn - zloc[j]);
        float alpha = 1.0f - __expf(-sloc[j] * dist);
        float w     = alpha * T;
        T *= (1.0f - alpha + 1e-10f);
        ar = fmaf(w, rloc[3 * j + 0], ar);
        ag = fmaf(w, rloc[3 * j + 1], ag);
        ab = fmaf(w, rloc[3 * j + 2], ab);
        ad = fmaf(w, zloc[j], ad);
    }

    // ---- prefix product of segment transmittance across the 4 lanes ----
    const int  base = lane & ~3;
    const float P   = T;
    const float P0  = __shfl(P, base + 0);
    const float P1  = __shfl(P, base + 1);
    const float P2  = __shfl(P, base + 2);
    float Tpre = 1.0f;
    if (q > 0) Tpre *= P0;
    if (q > 1) Tpre *= P1;
    if (q > 2) Tpre *= P2;

    ar *= Tpre; ag *= Tpre; ab *= Tpre; ad *= Tpre;

    // ---- reduce the 4 lanes of each ray ----
    ar += __shfl_xor(ar, 1); ag += __shfl_xor(ag, 1);
    ab += __shfl_xor(ab, 1); ad += __shfl_xor(ad, 1);
    ar += __shfl_xor(ar, 2); ag += __shfl_xor(ag, 2);
    ab += __shfl_xor(ab, 2); ad += __shfl_xor(ad, 2);

    if (q == 0 && ray < n_rays) {
        out_rgb[(size_t)ray * 3 + 0] = ar;
        out_rgb[(size_t)ray * 3 + 1] = ag;
        out_rgb[(size_t)ray * 3 + 2] = ab;
        out_depth[ray] = ad;
    }
}

extern "C" void kernel_launch(void* const* d_in, const int* in_sizes, int n_in,
                              void* d_out, int out_size, void* d_ws, size_t ws_size,
                              hipStream_t stream) {
    const float4* rgb4   = (const float4*)d_in[0];  // (B,HW,48,3) f32
    const float4* sigma4 = (const float4*)d_in[1];  // (B,HW,48,1) f32
    const float4* z4     = (const float4*)d_in[2];  // (B,HW,48)   f32

    const int n_rays = in_sizes[2] / N_SAMP;

    float* out_rgb   = (float*)d_out;
    float* out_depth = out_rgb + (size_t)n_rays * 3;

    const int grid = (n_rays + RPB - 1) / RPB;   // 4096 blocks for 262144 rays
    hipLaunchKernelGGL(volrender_kernel, dim3(grid), dim3(BLOCK), 0, stream,
                       rgb4, sigma4, z4, out_rgb, out_depth, n_rays);
}

// Round 2
// 276.634 us; speedup vs baseline: 1.0143x; 1.0143x over previous
//
#include <hip/hip_runtime.h>

#define N_SAMP 48
#define TPR 4               // threads per ray
#define ROUNDS 3            // float4-chunks per thread
#define CSZ 4               // samples per chunk (one float4 of z/sigma)
#define RPB 64              // rays per block
#define BLOCK (RPB * TPR)   // 256 threads

// Coalesced register-resident kernel.
// Ownership: thread q of a ray owns sample-chunks c = q, q+4, q+8 (4 samples
// each). For a fixed unrolled load index, the 4 lanes of a ray read ADJACENT
// float4s, so z/sigma wave-instructions touch 16 cache lines (perfect) and
// rgb 48 (vs 64 for the contiguous-fragment mapping). All 15 loads are pinned
// BEFORE compute with sched_barrier(0) so the compiler cannot sink them into
// the scan chain (round-1 symptom: VGPR=32, per-iteration latency exposure).
// The per-ray scan is two-level: sequential inside each 4-sample chunk,
// shuffle-based exclusive prefix-product across the 12 chunks.
__global__ __launch_bounds__(BLOCK) void volrender_kernel(
    const float4* __restrict__ rgb4,    // n_rays * 36 float4
    const float4* __restrict__ sigma4,  // n_rays * 12 float4
    const float4* __restrict__ z4,      // n_rays * 12 float4
    float* __restrict__ out_rgb,        // n_rays * 3 floats
    float* __restrict__ out_depth,      // n_rays floats
    int n_rays)
{
    const int t    = threadIdx.x;
    const int rl   = t >> 2;     // ray within block
    const int q    = t & 3;      // lane's chunk slot within each round
    const int ray  = blockIdx.x * RPB + rl;
    const int rayc = (ray < n_rays) ? ray : (n_rays - 1);

    float zloc[ROUNDS][CSZ];        // z of chunk (4r+q)
    float sloc[ROUNDS][CSZ];        // sigma of chunk (4r+q)
    float rloc[ROUNDS][CSZ * 3];    // rgb of chunk (4r+q)

    // ---- all global loads issued up front, z first (first consumed) ----
    {
        const size_t zb = (size_t)rayc * 12 + q;     // float4 units
#pragma unroll
        for (int r = 0; r < ROUNDS; ++r)
            *reinterpret_cast<float4*>(zloc[r]) = z4[zb + 4 * r];
#pragma unroll
        for (int r = 0; r < ROUNDS; ++r)
            *reinterpret_cast<float4*>(sloc[r]) = sigma4[zb + 4 * r];
        const size_t rb = (size_t)rayc * 36 + 3 * q; // float4 units
#pragma unroll
        for (int r = 0; r < ROUNDS; ++r)
#pragma unroll
            for (int k = 0; k < 3; ++k)
                reinterpret_cast<float4*>(rloc[r])[k] = rgb4[rb + 12 * r + k];
    }
    __builtin_amdgcn_sched_barrier(0);   // loads stay above, compute below

    const int lane = t & 63;
    const int base = lane & ~3;

    // ---- z of the first sample of chunk c+1, for each of this thread's chunks
    // A[r] = shfl(zloc[r][0], base + (q+1)&3):
    //   q<3 -> lane q+1, same round (chunk c+1)           [correct]
    //   q=3 -> lane 0, same round; actual next chunk is lane 0, round r+1,
    //          so q==3 uses A[r+1] instead (chunk 4(r+1)). A[2] for (q=3,r=2)
    //          is never consumed (global last sample -> dist = 1e10).
    float A[ROUNDS];
#pragma unroll
    for (int r = 0; r < ROUNDS; ++r)
        A[r] = __shfl(zloc[r][0], base + ((q + 1) & 3));

    // ---- per-chunk local pass: weights with chunk-local exclusive T ----
    float Q[ROUNDS];                         // chunk transmittance product
    float car[ROUNDS], cag[ROUNDS], cab[ROUNDS], cad[ROUNDS];
#pragma unroll
    for (int r = 0; r < ROUNDS; ++r) {
        const float znext = (q < 3) ? A[r] : A[(r < ROUNDS - 1) ? r + 1 : r];
        float T = 1.0f, ar = 0.0f, ag = 0.0f, ab = 0.0f, ad = 0.0f;
#pragma unroll
        for (int j = 0; j < CSZ; ++j) {
            const float zn   = (j < CSZ - 1) ? zloc[r][j + 1] : znext;
            const bool  gl   = (r == ROUNDS - 1) && (q == TPR - 1) && (j == CSZ - 1);
            const float dist = gl ? 1e10f : (zn - zloc[r][j]);
            const float alpha = 1.0f - __expf(-sloc[r][j] * dist);
            const float w     = alpha * T;
            T *= (1.0f - alpha + 1e-10f);
            ar = fmaf(w, rloc[r][3 * j + 0], ar);
            ag = fmaf(w, rloc[r][3 * j + 1], ag);
            ab = fmaf(w, rloc[r][3 * j + 2], ab);
            ad = fmaf(w, zloc[r][j], ad);
        }
        Q[r] = T;
        car[r] = ar; cag[r] = ag; cab[r] = ab; cad[r] = ad;
    }

    // ---- exclusive prefix product over the 12 chunks ----
    float pre[ROUNDS], R[ROUNDS];
#pragma unroll
    for (int r = 0; r < ROUNDS; ++r) {
        const float q0 = __shfl(Q[r], base + 0);
        const float q1 = __shfl(Q[r], base + 1);
        const float q2 = __shfl(Q[r], base + 2);
        const float q3 = __shfl(Q[r], base + 3);
        float p = 1.0f;
        if (q > 0) p *= q0;
        if (q > 1) p *= q1;
        if (q > 2) p *= q2;
        pre[r] = p;
        R[r]   = q0 * q1 * q2 * q3;          // R[2] dead, DCE'd
    }
    const float S0 = pre[0];
    const float S1 = R[0] * pre[1];
    const float S2 = R[0] * R[1] * pre[2];

    float ar = S0 * car[0]; ar = fmaf(S1, car[1], ar); ar = fmaf(S2, car[2], ar);
    float ag = S0 * cag[0]; ag = fmaf(S1, cag[1], ag); ag = fmaf(S2, cag[2], ag);
    float ab = S0 * cab[0]; ab = fmaf(S1, cab[1], ab); ab = fmaf(S2, cab[2], ab);
    float ad = S0 * cad[0]; ad = fmaf(S1, cad[1], ad); ad = fmaf(S2, cad[2], ad);

    // ---- reduce the 4 lanes of each ray ----
    ar += __shfl_xor(ar, 1); ag += __shfl_xor(ag, 1);
    ab += __shfl_xor(ab, 1); ad += __shfl_xor(ad, 1);
    ar += __shfl_xor(ar, 2); ag += __shfl_xor(ag, 2);
    ab += __shfl_xor(ab, 2); ad += __shfl_xor(ad, 2);

    if (q == 0 && ray < n_rays) {
        out_rgb[(size_t)ray * 3 + 0] = ar;
        out_rgb[(size_t)ray * 3 + 1] = ag;
        out_rgb[(size_t)ray * 3 + 2] = ab;
        out_depth[ray] = ad;
    }
}

extern "C" void kernel_launch(void* const* d_in, const int* in_sizes, int n_in,
                              void* d_out, int out_size, void* d_ws, size_t ws_size,
                              hipStream_t stream) {
    const float4* rgb4   = (const float4*)d_in[0];  // (B,HW,48,3) f32
    const float4* sigma4 = (const float4*)d_in[1];  // (B,HW,48,1) f32
    const float4* z4     = (const float4*)d_in[2];  // (B,HW,48)   f32

    const int n_rays = in_sizes[2] / N_SAMP;

    float* out_rgb   = (float*)d_out;
    float* out_depth = out_rgb + (size_t)n_rays * 3;

    const int grid = (n_rays + RPB - 1) / RPB;   // 4096 blocks for 262144 rays
    hipLaunchKernelGGL(volrender_kernel, dim3(grid), dim3(BLOCK), 0, stream,
                       rgb4, sigma4, z4, out_rgb, out_depth, n_rays);
}

// Round 3
// 275.043 us; speedup vs baseline: 1.0202x; 1.0058x over previous
//
#include <hip/hip_runtime.h>

#define N_SAMP 48
#define TPR 4               // threads per ray
#define ROUNDS 3            // float4-chunks per thread
#define CSZ 4               // samples per chunk (one float4 of z/sigma)
#define RPB 64              // rays per block
#define BLOCK (RPB * TPR)   // 256 threads

// Round-3 experiment: round-2 coalesced chunk mapping + HARD liveness pin on
// all 15 load results. Rounds 1-2 showed VGPR=32/40: the compiler sank the
// loads into the scan chain, so each wave only had ~3 loads in flight and the
// kernel ran latency-serialized. The asm keep-alives below ("+v" on every
// loaded float, "memory" clobber) make sinking illegal: all 15 float4 loads
// must issue before any compute, giving 15 outstanding loads/wave at ~4
// waves/SIMD (~60/SIMD vs ~15 before).
#define KEEP4(a, b, c, d) \
    asm volatile("" : "+v"(a), "+v"(b), "+v"(c), "+v"(d) :: "memory")

__global__ __launch_bounds__(BLOCK) void volrender_kernel(
    const float4* __restrict__ rgb4,    // n_rays * 36 float4
    const float4* __restrict__ sigma4,  // n_rays * 12 float4
    const float4* __restrict__ z4,      // n_rays * 12 float4
    float* __restrict__ out_rgb,        // n_rays * 3 floats
    float* __restrict__ out_depth,      // n_rays floats
    int n_rays)
{
    const int t    = threadIdx.x;
    const int rl   = t >> 2;     // ray within block
    const int q    = t & 3;      // lane's chunk slot within each round
    const int ray  = blockIdx.x * RPB + rl;
    const int rayc = (ray < n_rays) ? ray : (n_rays - 1);

    float zloc[ROUNDS][CSZ];        // z of chunk (4r+q)
    float sloc[ROUNDS][CSZ];        // sigma of chunk (4r+q)
    float rloc[ROUNDS][CSZ * 3];    // rgb of chunk (4r+q)

    // ---- all global loads issued up front ----
    {
        const size_t zb = (size_t)rayc * 12 + q;     // float4 units
#pragma unroll
        for (int r = 0; r < ROUNDS; ++r)
            *reinterpret_cast<float4*>(zloc[r]) = z4[zb + 4 * r];
#pragma unroll
        for (int r = 0; r < ROUNDS; ++r)
            *reinterpret_cast<float4*>(sloc[r]) = sigma4[zb + 4 * r];
        const size_t rb = (size_t)rayc * 36 + 3 * q; // float4 units
#pragma unroll
        for (int r = 0; r < ROUNDS; ++r)
#pragma unroll
            for (int k = 0; k < 3; ++k)
                reinterpret_cast<float4*>(rloc[r])[k] = rgb4[rb + 12 * r + k];
    }

    // ---- liveness pin: every loaded float must be materialized here ----
#pragma unroll
    for (int r = 0; r < ROUNDS; ++r) {
        KEEP4(zloc[r][0], zloc[r][1], zloc[r][2], zloc[r][3]);
        KEEP4(sloc[r][0], sloc[r][1], sloc[r][2], sloc[r][3]);
        KEEP4(rloc[r][0], rloc[r][1], rloc[r][2],  rloc[r][3]);
        KEEP4(rloc[r][4], rloc[r][5], rloc[r][6],  rloc[r][7]);
        KEEP4(rloc[r][8], rloc[r][9], rloc[r][10], rloc[r][11]);
    }
    __builtin_amdgcn_sched_barrier(0);   // loads stay above, compute below

    const int lane = t & 63;
    const int base = lane & ~3;

    // ---- z of the first sample of chunk c+1, for each of this thread's chunks
    float A[ROUNDS];
#pragma unroll
    for (int r = 0; r < ROUNDS; ++r)
        A[r] = __shfl(zloc[r][0], base + ((q + 1) & 3));

    // ---- per-chunk local pass: weights with chunk-local exclusive T ----
    float Q[ROUNDS];                         // chunk transmittance product
    float car[ROUNDS], cag[ROUNDS], cab[ROUNDS], cad[ROUNDS];
#pragma unroll
    for (int r = 0; r < ROUNDS; ++r) {
        const float znext = (q < 3) ? A[r] : A[(r < ROUNDS - 1) ? r + 1 : r];
        float T = 1.0f, ar = 0.0f, ag = 0.0f, ab = 0.0f, ad = 0.0f;
#pragma unroll
        for (int j = 0; j < CSZ; ++j) {
            const float zn   = (j < CSZ - 1) ? zloc[r][j + 1] : znext;
            const bool  gl   = (r == ROUNDS - 1) && (q == TPR - 1) && (j == CSZ - 1);
            const float dist = gl ? 1e10f : (zn - zloc[r][j]);
            const float alpha = 1.0f - __expf(-sloc[r][j] * dist);
            const float w     = alpha * T;
            T *= (1.0f - alpha + 1e-10f);
            ar = fmaf(w, rloc[r][3 * j + 0], ar);
            ag = fmaf(w, rloc[r][3 * j + 1], ag);
            ab = fmaf(w, rloc[r][3 * j + 2], ab);
            ad = fmaf(w, zloc[r][j], ad);
        }
        Q[r] = T;
        car[r] = ar; cag[r] = ag; cab[r] = ab; cad[r] = ad;
    }

    // ---- exclusive prefix product over the 12 chunks ----
    float pre[ROUNDS], R[ROUNDS];
#pragma unroll
    for (int r = 0; r < ROUNDS; ++r) {
        const float q0 = __shfl(Q[r], base + 0);
        const float q1 = __shfl(Q[r], base + 1);
        const float q2 = __shfl(Q[r], base + 2);
        const float q3 = __shfl(Q[r], base + 3);
        float p = 1.0f;
        if (q > 0) p *= q0;
        if (q > 1) p *= q1;
        if (q > 2) p *= q2;
        pre[r] = p;
        R[r]   = q0 * q1 * q2 * q3;
    }
    const float S0 = pre[0];
    const float S1 = R[0] * pre[1];
    const float S2 = R[0] * R[1] * pre[2];

    float ar = S0 * car[0]; ar = fmaf(S1, car[1], ar); ar = fmaf(S2, car[2], ar);
    float ag = S0 * cag[0]; ag = fmaf(S1, cag[1], ag); ag = fmaf(S2, cag[2], ag);
    float ab = S0 * cab[0]; ab = fmaf(S1, cab[1], ab); ab = fmaf(S2, cab[2], ab);
    float ad = S0 * cad[0]; ad = fmaf(S1, cad[1], ad); ad = fmaf(S2, cad[2], ad);

    // ---- reduce the 4 lanes of each ray ----
    ar += __shfl_xor(ar, 1); ag += __shfl_xor(ag, 1);
    ab += __shfl_xor(ab, 1); ad += __shfl_xor(ad, 1);
    ar += __shfl_xor(ar, 2); ag += __shfl_xor(ag, 2);
    ab += __shfl_xor(ab, 2); ad += __shfl_xor(ad, 2);

    if (q == 0 && ray < n_rays) {
        out_rgb[(size_t)ray * 3 + 0] = ar;
        out_rgb[(size_t)ray * 3 + 1] = ag;
        out_rgb[(size_t)ray * 3 + 2] = ab;
        out_depth[ray] = ad;
    }
}

extern "C" void kernel_launch(void* const* d_in, const int* in_sizes, int n_in,
                              void* d_out, int out_size, void* d_ws, size_t ws_size,
                              hipStream_t stream) {
    const float4* rgb4   = (const float4*)d_in[0];  // (B,HW,48,3) f32
    const float4* sigma4 = (const float4*)d_in[1];  // (B,HW,48,1) f32
    const float4* z4     = (const float4*)d_in[2];  // (B,HW,48)   f32

    const int n_rays = in_sizes[2] / N_SAMP;

    float* out_rgb   = (float*)d_out;
    float* out_depth = out_rgb + (size_t)n_rays * 3;

    const int grid = (n_rays + RPB - 1) / RPB;   // 4096 blocks for 262144 rays
    hipLaunchKernelGGL(volrender_kernel, dim3(grid), dim3(BLOCK), 0, stream,
                       rgb4, sigma4, z4, out_rgb, out_depth, n_rays);
}

// Round 4
// 274.708 us; speedup vs baseline: 1.0214x; 1.0012x over previous
//
#include <hip/hip_runtime.h>

#define N_SAMP 48
#define TPR 4               // threads per ray
#define ROUNDS 3            // float4-chunks per thread
#define CSZ 4               // samples per chunk (one float4 of z/sigma)
#define RPB 64              // rays per block
#define BLOCK (RPB * TPR)   // 256 threads

typedef float vf4 __attribute__((ext_vector_type(4)));

// Round-4 experiment: round-2 kernel with NON-TEMPORAL input loads.
// Theory: inputs (252 MB) marginally fit the 256 MB Infinity Cache; steady
// state serves ~half from L3 with constant eviction churn, and both the L3-hit
// and HBM paths sit at ~1.3 TB/s while no visible counter saturates. nt loads
// (evict-first / no-retain) take the L3 allocation+churn machinery out of the
// loop: all traffic should come from HBM on the measured-good streaming path.
// Proof counter: FETCH_SIZE 123 MB -> ~252 MB.
__global__ __launch_bounds__(BLOCK) void volrender_kernel(
    const vf4* __restrict__ rgb4,    // n_rays * 36 float4
    const vf4* __restrict__ sigma4,  // n_rays * 12 float4
    const vf4* __restrict__ z4,      // n_rays * 12 float4
    float* __restrict__ out_rgb,     // n_rays * 3 floats
    float* __restrict__ out_depth,   // n_rays floats
    int n_rays)
{
    const int t    = threadIdx.x;
    const int rl   = t >> 2;     // ray within block
    const int q    = t & 3;      // lane's chunk slot within each round
    const int ray  = blockIdx.x * RPB + rl;
    const int rayc = (ray < n_rays) ? ray : (n_rays - 1);

    float zloc[ROUNDS][CSZ];        // z of chunk (4r+q)
    float sloc[ROUNDS][CSZ];        // sigma of chunk (4r+q)
    float rloc[ROUNDS][CSZ * 3];    // rgb of chunk (4r+q)

    // ---- all global loads issued up front, non-temporal ----
    {
        const size_t zb = (size_t)rayc * 12 + q;     // float4 units
#pragma unroll
        for (int r = 0; r < ROUNDS; ++r)
            *reinterpret_cast<vf4*>(zloc[r]) = __builtin_nontemporal_load(&z4[zb + 4 * r]);
#pragma unroll
        for (int r = 0; r < ROUNDS; ++r)
            *reinterpret_cast<vf4*>(sloc[r]) = __builtin_nontemporal_load(&sigma4[zb + 4 * r]);
        const size_t rb = (size_t)rayc * 36 + 3 * q; // float4 units
#pragma unroll
        for (int r = 0; r < ROUNDS; ++r)
#pragma unroll
            for (int k = 0; k < 3; ++k)
                reinterpret_cast<vf4*>(rloc[r])[k] = __builtin_nontemporal_load(&rgb4[rb + 12 * r + k]);
    }
    __builtin_amdgcn_sched_barrier(0);   // loads stay above, compute below

    const int lane = t & 63;
    const int base = lane & ~3;

    // ---- z of the first sample of chunk c+1, for each of this thread's chunks
    // q<3 -> lane q+1, same round (chunk c+1); q==3 -> lane 0 of round r+1.
    float A[ROUNDS];
#pragma unroll
    for (int r = 0; r < ROUNDS; ++r)
        A[r] = __shfl(zloc[r][0], base + ((q + 1) & 3));

    // ---- per-chunk local pass: weights with chunk-local exclusive T ----
    float Q[ROUNDS];                         // chunk transmittance product
    float car[ROUNDS], cag[ROUNDS], cab[ROUNDS], cad[ROUNDS];
#pragma unroll
    for (int r = 0; r < ROUNDS; ++r) {
        const float znext = (q < 3) ? A[r] : A[(r < ROUNDS - 1) ? r + 1 : r];
        float T = 1.0f, ar = 0.0f, ag = 0.0f, ab = 0.0f, ad = 0.0f;
#pragma unroll
        for (int j = 0; j < CSZ; ++j) {
            const float zn   = (j < CSZ - 1) ? zloc[r][j + 1] : znext;
            const bool  gl   = (r == ROUNDS - 1) && (q == TPR - 1) && (j == CSZ - 1);
            const float dist = gl ? 1e10f : (zn - zloc[r][j]);
            const float alpha = 1.0f - __expf(-sloc[r][j] * dist);
            const float w     = alpha * T;
            T *= (1.0f - alpha + 1e-10f);
            ar = fmaf(w, rloc[r][3 * j + 0], ar);
            ag = fmaf(w, rloc[r][3 * j + 1], ag);
            ab = fmaf(w, rloc[r][3 * j + 2], ab);
            ad = fmaf(w, zloc[r][j], ad);
        }
        Q[r] = T;
        car[r] = ar; cag[r] = ag; cab[r] = ab; cad[r] = ad;
    }

    // ---- exclusive prefix product over the 12 chunks ----
    float pre[ROUNDS], R[ROUNDS];
#pragma unroll
    for (int r = 0; r < ROUNDS; ++r) {
        const float q0 = __shfl(Q[r], base + 0);
        const float q1 = __shfl(Q[r], base + 1);
        const float q2 = __shfl(Q[r], base + 2);
        const float q3 = __shfl(Q[r], base + 3);
        float p = 1.0f;
        if (q > 0) p *= q0;
        if (q > 1) p *= q1;
        if (q > 2) p *= q2;
        pre[r] = p;
        R[r]   = q0 * q1 * q2 * q3;
    }
    const float S0 = pre[0];
    const float S1 = R[0] * pre[1];
    const float S2 = R[0] * R[1] * pre[2];

    float ar = S0 * car[0]; ar = fmaf(S1, car[1], ar); ar = fmaf(S2, car[2], ar);
    float ag = S0 * cag[0]; ag = fmaf(S1, cag[1], ag); ag = fmaf(S2, cag[2], ag);
    float ab = S0 * cab[0]; ab = fmaf(S1, cab[1], ab); ab = fmaf(S2, cab[2], ab);
    float ad = S0 * cad[0]; ad = fmaf(S1, cad[1], ad); ad = fmaf(S2, cad[2], ad);

    // ---- reduce the 4 lanes of each ray ----
    ar += __shfl_xor(ar, 1); ag += __shfl_xor(ag, 1);
    ab += __shfl_xor(ab, 1); ad += __shfl_xor(ad, 1);
    ar += __shfl_xor(ar, 2); ag += __shfl_xor(ag, 2);
    ab += __shfl_xor(ab, 2); ad += __shfl_xor(ad, 2);

    if (q == 0 && ray < n_rays) {
        __builtin_nontemporal_store(ar, &out_rgb[(size_t)ray * 3 + 0]);
        __builtin_nontemporal_store(ag, &out_rgb[(size_t)ray * 3 + 1]);
        __builtin_nontemporal_store(ab, &out_rgb[(size_t)ray * 3 + 2]);
        __builtin_nontemporal_store(ad, &out_depth[ray]);
    }
}

extern "C" void kernel_launch(void* const* d_in, const int* in_sizes, int n_in,
                              void* d_out, int out_size, void* d_ws, size_t ws_size,
                              hipStream_t stream) {
    const vf4* rgb4   = (const vf4*)d_in[0];  // (B,HW,48,3) f32
    const vf4* sigma4 = (const vf4*)d_in[1];  // (B,HW,48,1) f32
    const vf4* z4     = (const vf4*)d_in[2];  // (B,HW,48)   f32

    const int n_rays = in_sizes[2] / N_SAMP;

    float* out_rgb   = (float*)d_out;
    float* out_depth = out_rgb + (size_t)n_rays * 3;

    const int grid = (n_rays + RPB - 1) / RPB;   // 4096 blocks for 262144 rays
    hipLaunchKernelGGL(volrender_kernel, dim3(grid), dim3(BLOCK), 0, stream,
                       rgb4, sigma4, z4, out_rgb, out_depth, n_rays);
}